// Round 1
// baseline (125.230 us; speedup 1.0000x reference)
//
#include <hip/hip_runtime.h>

// Problem constants (fixed by setup_inputs)
#define T_DIM 32
#define B_DIM 64
#define D_DIM 256
#define P_DIM 1024
#define NK    17
#define DT    0.1875f   // 3/16

// ---------------------------------------------------------------------------
// Kernel 1: inverse column norms of A (applied later as a scale on x = proj@A)
// grid 16 x 256 threads: 64 columns per block, d split 4-ways across waves
// ---------------------------------------------------------------------------
__global__ __launch_bounds__(256) void col_norm_kernel(const float* __restrict__ A,
                                                       float* __restrict__ inv_norm) {
  __shared__ float red[4][64];
  const int pl = threadIdx.x & 63;
  const int ch = threadIdx.x >> 6;
  const int p  = blockIdx.x * 64 + pl;
  const int d0 = ch * 64;
  float s = 0.f;
#pragma unroll 8
  for (int d = d0; d < d0 + 64; ++d) {
    float v = A[d * P_DIM + p];          // coalesced across lanes
    s = fmaf(v, v, s);
  }
  red[ch][pl] = s;
  __syncthreads();
  if (threadIdx.x < 64) {
    float tot = red[0][pl] + red[1][pl] + red[2][pl] + red[3][pl];
    inv_norm[p] = 1.f / fmaxf(sqrtf(tot), 1e-12f);
  }
}

// ---------------------------------------------------------------------------
// Kernel 2: fused  x = proj@A * inv_norm ; cos/sin sums over B ; err ; reduce
// grid (16 p-tiles, 32 t) x 256 threads. lane = p within tile, wave = b-quarter.
// LDS: 64KB, phase A = A-tile [d][64], then reused for partial-sum combine.
// ---------------------------------------------------------------------------
__global__ __launch_bounds__(256) void sig_main_kernel(const float* __restrict__ proj,
                                                       const float* __restrict__ A,
                                                       const float* __restrict__ inv_norm,
                                                       float* __restrict__ out) {
  __shared__ float smem[16384];          // 64 KB
  const int tid  = threadIdx.x;
  const int lane = tid & 63;
  const int wave = tid >> 6;
  const int p0   = blockIdx.x * 64;
  const int t    = blockIdx.y;

  // ---- stage A tile into LDS: smem[d*64 + pl] = A[d][p0+pl] ----
  {
    const float4* A4 = (const float4*)(A + p0);   // row stride = 256 float4
    float4* s4 = (float4*)smem;
#pragma unroll
    for (int r = 0; r < 16; ++r) {
      int i = tid + r * 256;             // i in [0,4096)
      int d = i >> 4;
      int c = i & 15;
      s4[i] = A4[d * (P_DIM / 4) + c];
    }
  }
  __syncthreads();

  // ---- phase A: xacc[j] = sum_d proj[t][b0+j][d] * A[d][p0+lane] ----
  const int b0 = wave * 16;
  float xacc[16];
#pragma unroll
  for (int j = 0; j < 16; ++j) xacc[j] = 0.f;

  const float* projbase = proj + ((size_t)(t * B_DIM + b0)) * D_DIM;

  for (int d = 0; d < D_DIM; d += 4) {
    float a0 = smem[(d + 0) * 64 + lane];    // lane-consecutive: conflict-free
    float a1 = smem[(d + 1) * 64 + lane];
    float a2 = smem[(d + 2) * 64 + lane];
    float a3 = smem[(d + 3) * 64 + lane];
#pragma unroll
    for (int j = 0; j < 16; ++j) {
      float4 pj = *(const float4*)(projbase + j * D_DIM + d);  // wave-uniform
      xacc[j] = fmaf(pj.x, a0, xacc[j]);
      xacc[j] = fmaf(pj.y, a1, xacc[j]);
      xacc[j] = fmaf(pj.z, a2, xacc[j]);
      xacc[j] = fmaf(pj.w, a3, xacc[j]);
    }
  }

  // ---- phase B: trig via Chebyshev recurrence, accumulate over 16 b's ----
  const float inv = inv_norm[p0 + lane];
  float cs[NK], ss[NK];
#pragma unroll
  for (int k = 0; k < NK; ++k) { cs[k] = 0.f; ss[k] = 0.f; }

#pragma unroll
  for (int j = 0; j < 16; ++j) {
    float x  = xacc[j] * inv;
    float th = x * DT;
    float s1, c1;
    __sincosf(th, &s1, &c1);
    float twoc = 2.f * c1;
    float ckm1 = 1.f, skm1 = 0.f;        // k = 0
    float ck = c1, sk = s1;              // k = 1
    cs[1] += c1;
    ss[1] += s1;
#pragma unroll
    for (int k = 2; k < NK; ++k) {
      float cn = fmaf(twoc, ck, -ckm1);
      float sn = fmaf(twoc, sk, -skm1);
      cs[k] += cn;
      ss[k] += sn;
      ckm1 = ck; skm1 = sk; ck = cn; sk = sn;
    }
  }
  cs[0] = 16.f;                          // cos(0)=1 summed over 16 b's
  ss[0] = 0.f;

  // ---- combine the 4 wave-partials in LDS (reuse A-tile region) ----
  __syncthreads();                       // everyone done reading A tile
  float* sred = smem;                    // [k][cos/sin][wave][lane] -> 8704 floats
#pragma unroll
  for (int k = 0; k < NK; ++k) {
    sred[((k * 2 + 0) * 4 + wave) * 64 + lane] = cs[k];
    sred[((k * 2 + 1) * 4 + wave) * 64 + lane] = ss[k];
  }
  __syncthreads();

  // ---- per-(k,p) error, weight-dot, scaled partial sum ----
  float part = 0.f;
  for (int e = tid; e < NK * 64; e += 256) {
    int k  = e >> 6;
    int pl = e & 63;
    const float* bc = &sred[((k * 2 + 0) * 4) * 64 + pl];
    const float* bs = &sred[((k * 2 + 1) * 4) * 64 + pl];
    float C = bc[0] + bc[64] + bc[128] + bc[192];
    float S = bs[0] + bs[64] + bs[128] + bs[192];
    float cm  = C * (1.f / 64.f);
    float sm  = S * (1.f / 64.f);
    float tk  = (float)k * DT;
    float phi = __expf(-0.5f * tk * tk);
    float w   = (((k == 0) || (k == NK - 1)) ? DT : 2.f * DT) * phi;
    float dc  = cm - phi;
    part = fmaf(w, fmaf(dc, dc, sm * sm), part);
  }
  part *= (1.f / 512.f);                 // * B / (T*P)

  // ---- block reduce (wave shuffle + LDS scratch above sred region) ----
#pragma unroll
  for (int off = 32; off > 0; off >>= 1)
    part += __shfl_down(part, off, 64);
  if (lane == 0) smem[8704 + wave] = part;   // disjoint from sred reads
  __syncthreads();
  if (tid == 0)
    atomicAdd(out, smem[8704] + smem[8705] + smem[8706] + smem[8707]);
}

// ---------------------------------------------------------------------------
extern "C" void kernel_launch(void* const* d_in, const int* in_sizes, int n_in,
                              void* d_out, int out_size, void* d_ws, size_t ws_size,
                              hipStream_t stream) {
  const float* proj = (const float*)d_in[0];   // (32,64,256) fp32
  const float* A    = (const float*)d_in[1];   // (256,1024) fp32
  float* inv_norm   = (float*)d_ws;            // 1024 floats scratch
  float* out        = (float*)d_out;           // 1 fp32 scalar

  hipMemsetAsync(out, 0, sizeof(float), stream);   // d_out is poisoned each call
  col_norm_kernel<<<dim3(16), dim3(256), 0, stream>>>(A, inv_norm);
  sig_main_kernel<<<dim3(16, 32), dim3(256), 0, stream>>>(proj, A, inv_norm, out);
}

// Round 2
// 86.386 us; speedup vs baseline: 1.4496x; 1.4496x over previous
//
#include <hip/hip_runtime.h>

// Problem constants (fixed by setup_inputs)
#define T_DIM 32
#define B_DIM 64
#define D_DIM 256
#define P_DIM 1024
#define NK    17
#define DT    0.1875f   // 3/16
#define NBLK  512       // 16 p-tiles x 32 t

// ---------------------------------------------------------------------------
// Main kernel: fused column-norm + x = proj@A*inv + cos/sin B-sums + weighted
// error -> one partial per block into ws.
// grid (16 ptile, 32 t) x 512 threads (8 waves; wave w handles b in [8w,8w+8)).
// LDS 64 KB reused three ways:
//   phase A (per d-chunk of 128): A-tile [128][64] @0 (32KB) + proj [64][128] @8192 (32KB)
//   reduction: cos sums [16][8][64] @0, sin sums [16][8][64] @8192 (k=0 plane
//   contributes exactly 0 to the statistic and is dropped)
// ---------------------------------------------------------------------------
__global__ __launch_bounds__(512) void sig_main_kernel(const float* __restrict__ proj,
                                                       const float* __restrict__ A,
                                                       float* __restrict__ partials) {
  __shared__ float smem[16384];          // 64 KB
  const int tid  = threadIdx.x;
  const int lane = tid & 63;
  const int wave = tid >> 6;             // 0..7
  const int p0   = blockIdx.x * 64;
  const int t    = blockIdx.y;

  float4* s4 = (float4*)smem;            // A-chunk as float4
  float4* p4 = (float4*)(smem + 8192);   // proj-chunk as float4

  float xacc[8];
#pragma unroll
  for (int j = 0; j < 8; ++j) xacc[j] = 0.f;
  float nacc = 0.f;                      // sum A[d][p]^2 (full d range)

  const float4* Ag = (const float4*)(A + p0);          // row stride 256 float4
  const float4* Pg = (const float4*)(proj + (size_t)t * B_DIM * D_DIM);

  for (int dc = 0; dc < D_DIM; dc += 128) {
    // ---- stage A chunk: smem[d*64 + pl] = A[dc+d][p0+pl], d in [0,128) ----
    // ---- stage proj chunk: smem_p[b*128 + d] = proj[t][b][dc+d] ----
#pragma unroll
    for (int r = 0; r < 4; ++r) {
      int i = tid + r * 512;             // i in [0,2048)
      int da = i >> 4, ca = i & 15;      // A: 16 float4 per 64-float row
      s4[i] = Ag[(dc + da) * (P_DIM / 4) + ca];
      int bp = i >> 5, cp = i & 31;      // proj: 32 float4 per 128-float row
      p4[i] = Pg[(size_t)bp * (D_DIM / 4) + dc / 4 + cp];
    }
    __syncthreads();

    // ---- phase A over this chunk ----
    const float4* prow = p4 + wave * 8 * 32;   // wave's 8 b-rows, 32 f4 each
#pragma unroll 2
    for (int ds4 = 0; ds4 < 32; ++ds4) {
      int dd = ds4 * 4;
      float a0 = smem[(dd + 0) * 64 + lane];   // 2-way bank alias: free
      float a1 = smem[(dd + 1) * 64 + lane];
      float a2 = smem[(dd + 2) * 64 + lane];
      float a3 = smem[(dd + 3) * 64 + lane];
      nacc = fmaf(a0, a0, nacc);
      nacc = fmaf(a1, a1, nacc);
      nacc = fmaf(a2, a2, nacc);
      nacc = fmaf(a3, a3, nacc);
#pragma unroll
      for (int j = 0; j < 8; ++j) {
        float4 pj = prow[j * 32 + ds4];        // wave-uniform: LDS broadcast
        xacc[j] = fmaf(pj.x, a0, xacc[j]);
        xacc[j] = fmaf(pj.y, a1, xacc[j]);
        xacc[j] = fmaf(pj.z, a2, xacc[j]);
        xacc[j] = fmaf(pj.w, a3, xacc[j]);
      }
    }
    __syncthreads();                     // done reading before re-stage / reuse
  }

  // ---- phase B: trig via Chebyshev recurrence over this lane's 8 b's ----
  const float inv = rsqrtf(fmaxf(nacc, 1e-24f));   // 1/clamp_min(norm,1e-12)
  float cs[NK], ss[NK];
#pragma unroll
  for (int k = 1; k < NK; ++k) { cs[k] = 0.f; ss[k] = 0.f; }

#pragma unroll
  for (int j = 0; j < 8; ++j) {
    float th = xacc[j] * inv * DT;
    float s1, c1;
    __sincosf(th, &s1, &c1);
    float twoc = 2.f * c1;
    float ckm1 = 1.f, skm1 = 0.f;        // k=0
    float ck = c1, sk = s1;              // k=1
    cs[1] += c1;
    ss[1] += s1;
#pragma unroll
    for (int k = 2; k < NK; ++k) {
      float cn = fmaf(twoc, ck, -ckm1);
      float sn = fmaf(twoc, sk, -skm1);
      cs[k] += cn;
      ss[k] += sn;
      ckm1 = ck; skm1 = sk; ck = cn; sk = sn;
    }
  }

  // ---- write wave-partial cos/sin sums (k=1..16 only; k=0 err is 0) ----
#pragma unroll
  for (int k = 1; k < NK; ++k) {
    int k1 = k - 1;
    smem[k1 * 512 + wave * 64 + lane]        = cs[k];   // cos plane
    smem[8192 + k1 * 512 + wave * 64 + lane] = ss[k];   // sin plane
  }
  __syncthreads();

  // ---- per-(k,p) error + weight dot; 1024 entries over 512 threads ----
  float part = 0.f;
#pragma unroll
  for (int r = 0; r < 2; ++r) {
    int e  = tid + r * 512;              // e in [0, 16*64)
    int k1 = e >> 6;
    int pl = e & 63;
    const float* bc = &smem[k1 * 512 + pl];
    const float* bs = &smem[8192 + k1 * 512 + pl];
    float C = 0.f, S = 0.f;
#pragma unroll
    for (int w = 0; w < 8; ++w) { C += bc[w * 64]; S += bs[w * 64]; }
    float cm  = C * (1.f / 64.f);
    float sm  = S * (1.f / 64.f);
    float tk  = (float)(k1 + 1) * DT;
    float phi = __expf(-0.5f * tk * tk);
    float wk  = ((k1 == NK - 2) ? DT : 2.f * DT) * phi;  // k=16 endpoint
    float dc  = cm - phi;
    part = fmaf(wk, fmaf(dc, dc, sm * sm), part);
  }
  part *= (1.f / 512.f);                 // * B / (T*P)

  // ---- block reduce ----
#pragma unroll
  for (int off = 32; off > 0; off >>= 1)
    part += __shfl_down(part, off, 64);
  __syncthreads();                       // everyone done reading sred planes
  if (lane == 0) smem[wave] = part;
  __syncthreads();
  if (tid == 0) {
    float s = 0.f;
#pragma unroll
    for (int w = 0; w < 8; ++w) s += smem[w];
    partials[blockIdx.y * 16 + blockIdx.x] = s;
  }
}

// ---------------------------------------------------------------------------
// Finalize: sum 512 block partials -> scalar
// ---------------------------------------------------------------------------
__global__ __launch_bounds__(256) void sig_finalize_kernel(const float* __restrict__ partials,
                                                           float* __restrict__ out) {
  __shared__ float red[4];
  const int tid  = threadIdx.x;
  const int lane = tid & 63;
  const int wave = tid >> 6;
  float v = partials[tid] + partials[tid + 256];
#pragma unroll
  for (int off = 32; off > 0; off >>= 1)
    v += __shfl_down(v, off, 64);
  if (lane == 0) red[wave] = v;
  __syncthreads();
  if (tid == 0) out[0] = red[0] + red[1] + red[2] + red[3];
}

// ---------------------------------------------------------------------------
extern "C" void kernel_launch(void* const* d_in, const int* in_sizes, int n_in,
                              void* d_out, int out_size, void* d_ws, size_t ws_size,
                              hipStream_t stream) {
  const float* proj = (const float*)d_in[0];   // (32,64,256) fp32
  const float* A    = (const float*)d_in[1];   // (256,1024) fp32
  float* partials   = (float*)d_ws;            // 512 floats scratch
  float* out        = (float*)d_out;           // 1 fp32 scalar

  sig_main_kernel<<<dim3(16, 32), dim3(512), 0, stream>>>(proj, A, partials);
  sig_finalize_kernel<<<dim3(1), dim3(256), 0, stream>>>(partials, out);
}